// Round 6
// baseline (253.123 us; speedup 1.0000x reference)
//
#include <hip/hip_runtime.h>
#include <stdint.h>

static constexpr int kN = 128;
static constexpr int kTri = (kN * (kN - 1)) / 2;   // 8128 (BT scratch indexing)
static constexpr int kTriD = (kN * (kN + 1)) / 2;  // 8256 cells incl. diagonal
static constexpr int kThreads = 1024;
static constexpr float kNeg = -9999.0f;
static constexpr float kThresh = -9000.0f;
static constexpr float kArcBonus = 5.0f;
static constexpr int kFlagInts = 5 * 17;           // per-phase [17] progress flags
static constexpr int kDynLds = kTriD * 16 + kFlagInts * 4;  // 132,436 B
static constexpr int kCMax = 9;                    // max row-cache slots per lane

__device__ __forceinline__ int rowBase(int i) { return (i * (2 * kN - 1 - i)) / 2; }
__device__ __forceinline__ int colBaseD(int c) { return (c * (c + 1)) / 2; }  // cells (r<=c, c)

// DPP cross-lane reduce helpers -- pure VALU, never touch the LDS pipe.
template <int CTRL>
__device__ __forceinline__ float dppMax(float x) {
    const int y = __builtin_amdgcn_update_dpp(__float_as_int(x), __float_as_int(x),
                                              CTRL, 0xF, 0xF, true);
    return fmaxf(x, __int_as_float(y));
}
template <int CTRL>
__device__ __forceinline__ int dppMinI(int x) {
    const int y = __builtin_amdgcn_update_dpp(x, x, CTRL, 0xF, 0xF, true);
    return (y < x) ? y : x;
}

// ---- Wave-pipeline sync (replaces per-step s_barrier) ----
// DP deps are strictly upward in span-start: cell (i, i+k) reads only cells
// (q, j) with q > i. Within a phase [k0,k1), in-phase reads hit groups
// q <= i + (k-k0), i.e. waves >= own. Protocol: wave w publishes completed
// step k to flag[w] AFTER s_waitcnt lgkmcnt(0); before step k it spins on
// flag[w+1] >= k-1 only. Transitivity: flag[w+1]>=k-1 => flag[w+J]>=k-J,
// and wave w+J's needed progress is k-(J-1)*G-1 <= k-J for any G>=1.
// Dead/groupless waves hold flag 127 (pre-init or published after their
// last drain), which terminates the chain soundly (their cells are never
// needed by construction: q < kN-k0 <= their first group).
__device__ __forceinline__ void spinWait(volatile const int* f, int need) {
    while (*f < need) __builtin_amdgcn_s_sleep(2);
    asm volatile("" ::: "memory");  // fence: no LDS reads hoist above the spin
}
__device__ __forceinline__ void publish(volatile int* f, int val, int laneId) {
    asm volatile("s_waitcnt lgkmcnt(0)" ::: "memory");  // drain cell writes first
    if (laneId == 0) *f = val;
}

// Static phase schedule (kN=128, 1024 threads): serial k<=16; P=8 k in
// [17,64); P=16 [64,128). P capped at 16 so all reductions are pure DPP.
__device__ __forceinline__ int lpOf(int k) {
    if (k <= 16) return 0;
    if (k < 64) return 3;
    return 4;
}
__device__ __forceinline__ void mapStatic(int nk, int tid, int& i, int& j, bool& act) {
    const int lp = lpOf(nk);
    i = tid >> lp;
    j = i + nk;
    act = i < (kN - nk);
}

// Quad per cell: {x=s00, y=s11, z=s01, w=s10}, col-major incl. diagonal (diag=0).
__device__ __forceinline__ float4 writeCell(float4* __restrict__ Q4,
                                            uint32_t* __restrict__ wsBT,
                                            int i, int j, int k,
                                            float gb, int ib, float vLc, float vRc,
                                            float v01, int i01, float v11, int i11) {
    const float v00 = (gb + vLc) + kArcBonus;
    const float v10 = (gb + vRc) + kArcBonus;
    const float new10 = (v10 > kThresh) ? v10 : kNeg;
    if (new10 > v11) { v11 = new10; i11 = k; }  // q=j candidate; strict > keeps earlier q
    float4 w = make_float4(kNeg, kNeg, kNeg, kNeg);
    uint32_t p = 0;
    if (v00 > kThresh) { w.x = v00; p |= (uint32_t)(i + ib); }
    if (v01 > kThresh) { w.z = v01; p |= (uint32_t)(i + i01) << 8; }
    if (v10 > kThresh) { w.w = v10; p |= (uint32_t)(i + ib) << 16; }
    if (v11 > kThresh) { w.y = v11; p |= (uint32_t)(i + i11) << 24; }
    Q4[colBaseD(j) + i] = w;          // one ds_write_b128
    wsBT[rowBase(i) + k - 1] = p;     // lone global store; drained at final barrier
    return w;
}

// Serial step (k<=16), k COMPILE-TIME: one thread per cell, i = tid fixed, all
// row operands are this thread's own prior outputs mirrored in sr[] registers.
__device__ __forceinline__ void doStepSerialReg(int k, int tid,
                                                float4* __restrict__ Q4,
                                                uint32_t* __restrict__ wsBT,
                                                const float* __restrict__ v,
                                                int& ci, int& cj, bool& cact,
                                                float& vL, float& vR,
                                                float (&sr11)[17], float (&sr01)[17],
                                                float (&sr10)[17]) {
    const int i = ci, j = cj;
    const bool act = cact;
    const float vLc = vL, vRc = vR;
    float bmax = -3.0e38f, v01 = -3.0e38f, v11 = -3.0e38f;
    int ib = 0, i01 = 0, i11 = 0x7FFFFFFF;
    if (act) {
        const int qjb = colBaseD(j);
        float4 cur = Q4[qjb + i + 1];  // quad(i+1, j); diagonal zeros when k==1
        bmax = cur.z; ib = 0;          // base(0) = 0 + s01[i+1][j]
        const float p00 = (cur.z + vLc) + kArcBonus;
        v01 = (p00 > kThresh) ? p00 : kNeg; i01 = 0;  // part00 seed
#pragma unroll
        for (int m = 1; m < 16; ++m) {
            if (m < k) {  // compile-time when k is constant-folded
                const float4 nxt = Q4[qjb + i + m + 1];  // quad(q+1, j)
                const float base = sr11[m] + nxt.z;      // s11[i][q] + s01[q+1][j]
                const float p01v = sr01[m] + cur.x;      // s01[i][q] + s00[q][j]
                const float p11v = sr10[m] + cur.y;      // s10[i][q] + s11[q][j]
                if (base > bmax) { bmax = base; ib = m; }  // strict > keeps earliest m
                if (p01v > v01) { v01 = p01v; i01 = m; }
                if (p11v > v11) { v11 = p11v; i11 = m; }
                cur = nxt;
            }
        }
    }
    if (k + 1 < kN) {
        mapStatic(k + 1, tid, ci, cj, cact);
        vL = cact ? v[cj * kN + ci] : 0.f;
        vR = cact ? v[ci * kN + cj] : 0.f;
    }
    if (act) {
        const float4 w = writeCell(Q4, wsBT, i, j, k, bmax, ib, vLc, vRc,
                                   v01, i01, v11, i11);
        sr11[k] = w.y; sr01[k] = w.z; sr10[k] = w.w;  // constant index (k unrolled)
    }
}

// ---- Chunked phases: register row-cache + fw forwarding (verified R4) ----
template <int LP, int C>
__device__ __forceinline__ void preloadRow(int k0, int tid,
                                           const float4* __restrict__ Q4,
                                           float (&r11)[kCMax], float (&r01)[kCMax],
                                           float (&r10)[kCMax]) {
    constexpr int P = 1 << LP;
    const int i = tid >> LP;
    const int l = tid & (P - 1);
    const int mlo = l * C;
    const int mstart = mlo ? mlo : 1;
    const bool act = i < (kN - k0);
#pragma unroll
    for (int c = 0; c < C; ++c) {
        const int m = mstart + c;
        if (act && (m < mlo + C) && (m <= k0 - 1)) {
            const float4 d = Q4[colBaseD(i + m) + i];  // quad(i, i+m), immutable
            r11[c] = d.y; r01[c] = d.z; r10[c] = d.w;
        }
    }
    // Slots with m > k0-1 stay stale: first read at step k=m+1 substitutes fw.
}

template <int LP, int C>
__device__ __forceinline__ void fwInit(int k0, int tid,
                                       const float (&r11)[kCMax], const float (&r01)[kCMax],
                                       const float (&r10)[kCMax],
                                       float& fw11, float& fw01, float& fw10) {
    constexpr int P = 1 << LP;
    const int l = tid & (P - 1);
    const int mlo = l * C;
    const int mstart = mlo ? mlo : 1;
#pragma unroll
    for (int c = 0; c < C; ++c) {
        if (mstart + c == k0 - 1) { fw11 = r11[c]; fw01 = r01[c]; fw10 = r10[c]; }
    }
}

template <int LP, int C>
__device__ __forceinline__ void doStepC(int k, int tid,
                                        float4* __restrict__ Q4,
                                        uint32_t* __restrict__ wsBT,
                                        const float* __restrict__ v,
                                        int& ci, int& cj, bool& cact,
                                        float& vL, float& vR,
                                        float (&r11)[kCMax], float (&r01)[kCMax],
                                        float (&r10)[kCMax],
                                        float& fw11, float& fw01, float& fw10) {
    constexpr int P = 1 << LP;
    static_assert(P <= 16, "reductions must stay pure-DPP");
    const int i = ci, j = cj;
    const bool act = cact;
    const float vLc = vL, vRc = vR;  // prefetch below overwrites vL/vR
    const int l = tid & (P - 1);
    const int mlo = l * C;
    const int mstart = mlo ? mlo : 1;
    const int mhi = (mlo + C < k) ? (mlo + C) : k;
    const bool waveActive = (((tid & ~63) >> LP) < (kN - k));  // wave-uniform

    float bmax = -3.0e38f, v01 = -3.0e38f, v11 = -3.0e38f;
    int ib = 0x7FFFFFFF, i01 = 0x7FFFFFFF, i11 = 0x7FFFFFFF;

    const int mf = k - 1;
    const bool lact = waveActive && act && (mstart < mhi);
    const int qjb = colBaseD(j);
    float4 cur = make_float4(0.f, 0.f, 0.f, 0.f);
    if (lact) cur = Q4[qjb + i + mstart];  // column seed quad(i+mstart, j)
    if (act && mlo == 0) {
        bmax = cur.z; ib = 0;  // base(0) = 0 + s01[i+1][j]
        const float p00 = (cur.z + vLc) + kArcBonus;
        v01 = (p00 > kThresh) ? p00 : kNeg; i01 = 0;  // part00 seed
    }
#pragma unroll
    for (int c = 0; c < C; ++c) {
        const int m = mstart + c;
        const bool isF = (m == mf);
        const float a11 = isF ? fw11 : r11[c];
        const float a01 = isF ? fw01 : r01[c];
        const float a10 = isF ? fw10 : r10[c];
        r11[c] = a11; r01[c] = a01; r10[c] = a10;
        const bool on = lact && (m < mhi);
        if (on) {
            const float4 nxt = Q4[qjb + i + m + 1];  // quad(q+1, j)
            const float base = a11 + nxt.z;          // s11[i][q] + s01[q+1][j]
            const float p01v = a01 + cur.x;          // s01[i][q] + s00[q][j]
            const float p11v = a10 + cur.y;          // s10[i][q] + s11[q][j]
            if (base > bmax) { bmax = base; ib = m; }  // strict > keeps earliest m
            if (p01v > v01) { v01 = p01v; i01 = m; }
            if (p11v > v11) { v11 = p11v; i11 = m; }
            cur = nxt;
        }
    }

    // Prefetch next step's mapping + vL/vR (overlaps reduction).
    if (k + 1 < kN) {
        mapStatic(k + 1, tid, ci, cj, cact);
        vL = cact ? v[cj * kN + ci] : 0.f;
        vR = cact ? v[ci * kN + cj] : 0.f;
    }

    if (waveActive) {
        // Value butterfly (pure DPP, VALU pipe only).
        float gB = dppMax<0x141>(dppMax<0x4E>(dppMax<0xB1>(bmax)));
        float g01 = dppMax<0x141>(dppMax<0x4E>(dppMax<0xB1>(v01)));
        float g11 = dppMax<0x141>(dppMax<0x4E>(dppMax<0xB1>(v11)));
        if constexpr (P == 16) {
            gB = dppMax<0x140>(gB); g01 = dppMax<0x140>(g01); g11 = dppMax<0x140>(g11);
        }
        // Earliest-m argmax: mask losers to INT_MAX, min-butterfly (pure DPP).
        int cB = (bmax == gB) ? ib : 0x7FFFFFFF;
        int c01 = (v01 == g01) ? i01 : 0x7FFFFFFF;
        int c11 = (v11 == g11) ? i11 : 0x7FFFFFFF;
        cB = dppMinI<0x141>(dppMinI<0x4E>(dppMinI<0xB1>(cB)));
        c01 = dppMinI<0x141>(dppMinI<0x4E>(dppMinI<0xB1>(c01)));
        c11 = dppMinI<0x141>(dppMinI<0x4E>(dppMinI<0xB1>(c11)));
        if constexpr (P == 16) {
            cB = dppMinI<0x140>(cB); c01 = dppMinI<0x140>(c01); c11 = dppMinI<0x140>(c11);
        }

        // All lanes hold the written-cell values -> fw for next step (m = k).
        const float v10f = (gB + vRc) + kArcBonus;
        const float new10 = (v10f > kThresh) ? v10f : kNeg;
        float v11m = g11;
        if (new10 > v11m) v11m = new10;
        fw11 = (v11m > kThresh) ? v11m : kNeg;  // w.y = s11(i,j)
        fw01 = (g01 > kThresh) ? g01 : kNeg;    // w.z = s01(i,j)
        fw10 = (v10f > kThresh) ? v10f : kNeg;  // w.w = s10(i,j)

        if (act && l == 0) {
            writeCell(Q4, wsBT, i, j, k, gB, cB, vLc, vRc, g01, c01, g11, c11);
        }
    }
}

// ---- Phase drivers (barrier-free inside; flag pipeline) ----
__device__ __forceinline__ void runPhaseSerial(int tid, int laneId, int w,
        float4* __restrict__ Q4, volatile int* flg,
        uint32_t* __restrict__ wsBT, const float* __restrict__ v) {
    if ((w << 6) >= kN - 1) return;  // waves 2..15 groupless (flag pre-init 127)
    int ci, cj; bool cact;
    mapStatic(1, tid, ci, cj, cact);
    float vL = cact ? v[cj * kN + ci] : 0.f;
    float vR = cact ? v[ci * kN + cj] : 0.f;
    float sr11[17], sr01[17], sr10[17];
#pragma unroll
    for (int k = 1; k <= 16; ++k) {
        spinWait(flg + (w + 1), k - 1);
        doStepSerialReg(k, tid, Q4, wsBT, v, ci, cj, cact, vL, vR, sr11, sr01, sr10);
        publish(flg + w, k, laneId);
    }
    // Both serial waves stay alive through k=16 (kD = 64, 128 > 16): no 127 needed;
    // phase boundary barrier follows.
}

template <int LP, int C>
__device__ __forceinline__ void runPhaseC(int k0, int k1, int tid, int laneId, int w,
        float4* __restrict__ Q4, volatile int* flg,
        uint32_t* __restrict__ wsBT, const float* __restrict__ v,
        float (&r11)[kCMax], float (&r01)[kCMax], float (&r10)[kCMax]) {
    const int firstGroup = (w << 6) >> LP;
    if (firstGroup >= kN - k0) return;  // groupless; flag pre-init 127
    int ci, cj; bool cact;
    mapStatic(k0, tid, ci, cj, cact);
    float vL = cact ? v[cj * kN + ci] : 0.f;
    float vR = cact ? v[ci * kN + cj] : 0.f;
    float fw11 = kNeg, fw01 = kNeg, fw10 = kNeg;
    preloadRow<LP, C>(k0, tid, Q4, r11, r01, r10);
    fwInit<LP, C>(k0, tid, r11, r01, r10, fw11, fw01, fw10);
    const int kD = kN - firstGroup;          // first k with this wave inactive
    const int kEnd = (k1 < kD) ? k1 : kD;
    for (int k = k0; k < kEnd; ++k) {
        spinWait(flg + (w + 1), k - 1);
        doStepC<LP, C>(k, tid, Q4, wsBT, v, ci, cj, cact, vL, vR,
                       r11, r01, r10, fw11, fw01, fw10);
        publish(flg + w, k, laneId);
    }
    if (kD < k1) publish(flg + w, 127, laneId);  // retire: terminate the chain
}

__global__ __launch_bounds__(kThreads) void eisner_dp(
    const float* __restrict__ vinfo,  // [B][N][N] fp32
    float* __restrict__ outS,         // [B][N][N][2][2] fp32 scores
    float* __restrict__ outBT,        // [B][N][N][2][2] fp32 backtrace (integer-valued)
    uint32_t* __restrict__ btPacked)  // [B][kTri] packed backtrace bytes (d_ws)
{
    extern __shared__ float4 Q4[];
    int* flagBase = (int*)(Q4 + kTriD);

    const int tid = threadIdx.x;
    const int laneId = tid & 63;
    const int w = tid >> 6;
    const int b = blockIdx.x;
    const float* v = vinfo + (size_t)b * kN * kN;
    uint32_t* wsBT = btPacked + (size_t)b * kTri;

    // Diagonal quads = 0. Off-diagonal cells need no init (written before read).
    const float4 zeroq = make_float4(0.f, 0.f, 0.f, 0.f);
    if (tid < kN) Q4[colBaseD(tid) + tid] = zeroq;

    // One-time flag init: per phase p, slot s: 127 if s is a groupless wave (or
    // the virtual wave 16); else k0(p)-1.
    if (tid < kFlagInts) {
        const int p = tid / 17, s = tid - p * 17;
        int k0v = 1, lp = 0;
        if (p == 1)      { k0v = 17;  lp = 3; }
        else if (p == 2) { k0v = 40;  lp = 3; }
        else if (p == 3) { k0v = 64;  lp = 4; }
        else if (p == 4) { k0v = 112; lp = 4; }
        int val = 127;
        if (s < 16) {
            const int fg = (s << 6) >> lp;
            if (fg < kN - k0v) val = k0v - 1;
        }
        flagBase[tid] = val;
    }
    __syncthreads();

    // Phase 0: serial (k=1..16), waves 0-1, flag-pipelined.
    runPhaseSerial(tid, laneId, w, Q4, flagBase + 0, wsBT, v);
    __syncthreads();

    float r11[kCMax], r01[kCMax], r10[kCMax];
#pragma unroll
    for (int c = 0; c < kCMax; ++c) { r11[c] = kNeg; r01[c] = kNeg; r10[c] = kNeg; }

    // Phase 1: P=8 C=5, k in [17,40).
    runPhaseC<3, 5>(17, 40, tid, laneId, w, Q4, flagBase + 17, wsBT, v, r11, r01, r10);
    __syncthreads();
    // Phase 2: P=8 C=9, k in [40,64).
    runPhaseC<3, 9>(40, 64, tid, laneId, w, Q4, flagBase + 34, wsBT, v, r11, r01, r10);
    __syncthreads();
    // Phase 3: P=16 C=7, k in [64,112).
    runPhaseC<4, 7>(64, 112, tid, laneId, w, Q4, flagBase + 51, wsBT, v, r11, r01, r10);
    __syncthreads();
    // Phase 4: P=16 C=9, k in [112,128).
    runPhaseC<4, 9>(112, 128, tid, laneId, w, Q4, flagBase + 68, wsBT, v, r11, r01, r10);

    // Full barrier (drains vmcnt) before reading wsBT back.
    __syncthreads();

    // ---- epilogue: emit full [N][N][2][2] scores + backtrace, coalesced ----
    float4* gS4 = (float4*)(outS + (size_t)b * kN * kN * 4);
    float4* gB4 = (float4*)(outBT + (size_t)b * kN * kN * 4);
    const float4 negq = make_float4(kNeg, kNeg, kNeg, kNeg);
    for (int c = tid; c < kN * kN; c += kThreads) {
        const int i = c >> 7, j = c & (kN - 1);
        if (i < j) {
            const float4 q = Q4[colBaseD(j) + i];
            gS4[c] = make_float4(q.x, q.z, q.w, q.y);  // {s00, s01, s10, s11}
            const uint32_t p = wsBT[rowBase(i) + (j - i - 1)];
            gB4[c] = make_float4((float)(p & 255u), (float)((p >> 8) & 255u),
                                 (float)((p >> 16) & 255u), (float)(p >> 24));
        } else if (i == j) {
            gS4[c] = zeroq;
            gB4[c] = zeroq;
        } else {
            gS4[c] = negq;
            gB4[c] = zeroq;
        }
    }
}

extern "C" void kernel_launch(void* const* d_in, const int* in_sizes, int n_in,
                              void* d_out, int out_size, void* d_ws, size_t ws_size,
                              hipStream_t stream) {
    (void)n_in; (void)out_size; (void)ws_size;
    const float* vinfo = (const float*)d_in[0];  // fp32 [B][N][N]
    const int B = in_sizes[1];                   // b_buffer_size has B elements
    float* outS = (float*)d_out;
    float* outBT = outS + (size_t)B * kN * kN * 4;
    uint32_t* btPacked = (uint32_t*)d_ws;        // needs B*kTri*4 = ~2.1 MB

    hipFuncSetAttribute(reinterpret_cast<const void*>(eisner_dp),
                        hipFuncAttributeMaxDynamicSharedMemorySize, kDynLds);

    eisner_dp<<<dim3(B), dim3(kThreads), kDynLds, stream>>>(vinfo, outS, outBT, btPacked);
}

// Round 7
// 230.530 us; speedup vs baseline: 1.0980x; 1.0980x over previous
//
#include <hip/hip_runtime.h>
#include <stdint.h>

static constexpr int kN = 128;
static constexpr int kTri = (kN * (kN - 1)) / 2;   // 8128 (BT scratch indexing)
static constexpr int kTriD = (kN * (kN + 1)) / 2;  // 8256 cells incl. diagonal
static constexpr int kThreads = 1024;
static constexpr float kNeg = -9999.0f;
static constexpr float kThresh = -9000.0f;
static constexpr float kArcBonus = 5.0f;
static constexpr int kDynLds = kTriD * 16;  // 132,096 B (one float4 quad per cell)
static constexpr int kCMax = 9;             // max row-cache slots per lane

__device__ __forceinline__ int rowBase(int i) { return (i * (2 * kN - 1 - i)) / 2; }
__device__ __forceinline__ int colBaseD(int c) { return (c * (c + 1)) / 2; }  // cells (r<=c, c)

// LDS-only workgroup barrier: orders LDS without draining vmcnt (wsBT stores
// and vL/vR prefetch loads stay in flight across steps).
__device__ __forceinline__ void ldsBarrier() {
    asm volatile("s_waitcnt lgkmcnt(0)\n\ts_barrier" ::: "memory");
}

// DPP cross-lane reduce helpers -- pure VALU, never touch the LDS pipe.
template <int CTRL>
__device__ __forceinline__ float dppMax(float x) {
    const int y = __builtin_amdgcn_update_dpp(__float_as_int(x), __float_as_int(x),
                                              CTRL, 0xF, 0xF, true);
    return fmaxf(x, __int_as_float(y));
}
template <int CTRL>
__device__ __forceinline__ int dppMinI(int x) {
    const int y = __builtin_amdgcn_update_dpp(x, x, CTRL, 0xF, 0xF, true);
    return (y < x) ? y : x;
}

// Quad per cell: {x=s00, y=s11, z=s01, w=s10}, col-major incl. diagonal (diag=0).
__device__ __forceinline__ float4 writeCell(float4* __restrict__ Q4,
                                            uint32_t* __restrict__ wsBT,
                                            int qjb, int i, int wsIdx, int k,
                                            float gb, int ib, float vLc, float vRc,
                                            float v01, int i01, float v11, int i11) {
    const float v00 = (gb + vLc) + kArcBonus;
    const float v10 = (gb + vRc) + kArcBonus;
    const float new10 = (v10 > kThresh) ? v10 : kNeg;
    if (new10 > v11) { v11 = new10; i11 = k; }  // q=j candidate; strict > keeps earlier q
    float4 w = make_float4(kNeg, kNeg, kNeg, kNeg);
    uint32_t p = 0;
    if (v00 > kThresh) { w.x = v00; p |= (uint32_t)(i + ib); }
    if (v01 > kThresh) { w.z = v01; p |= (uint32_t)(i + i01) << 8; }
    if (v10 > kThresh) { w.w = v10; p |= (uint32_t)(i + ib) << 16; }
    if (v11 > kThresh) { w.y = v11; p |= (uint32_t)(i + i11) << 24; }
    Q4[qjb + i] = w;      // one ds_write_b128
    wsBT[wsIdx] = p;      // lone global store; drained at the final __syncthreads
    return w;
}

// Serial step (k<=16), k COMPILE-TIME (caller unrolled): one thread per cell,
// i = tid fixed, all row operands are this thread's own prior outputs mirrored
// in sr[] registers. Incremental j/qjb/pL/pR (no per-step remap).
__device__ __forceinline__ void doStepSerialReg(int k, int i,
                                                float4* __restrict__ Q4,
                                                uint32_t* __restrict__ wsBT,
                                                int& j, int& qjb, int rbi,
                                                const float*& pL, const float*& pR,
                                                float& vL, float& vR,
                                                float (&sr11)[17], float (&sr01)[17],
                                                float (&sr10)[17]) {
    const bool act = i < kN - k;
    const float vLc = vL, vRc = vR;
    const int jc = j, qjbc = qjb;
    float bmax = -3.0e38f, v01 = -3.0e38f, v11 = -3.0e38f;
    int ib = 0, i01 = 0, i11 = 0x7FFFFFFF;
    if (act) {
        float4 cur = Q4[qjbc + i + 1];  // quad(i+1, j); diagonal zeros when k==1
        bmax = cur.z; ib = 0;           // base(0) = 0 + s01[i+1][j]
        const float p00 = (cur.z + vLc) + kArcBonus;
        v01 = (p00 > kThresh) ? p00 : kNeg; i01 = 0;  // part00 seed
#pragma unroll
        for (int m = 1; m < 16; ++m) {
            if (m < k) {  // compile-time when k is constant-folded
                const float4 nxt = Q4[qjbc + i + m + 1];  // quad(q+1, j)
                const float base = sr11[m] + nxt.z;       // s11[i][q] + s01[q+1][j]
                const float p01v = sr01[m] + cur.x;       // s01[i][q] + s00[q][j]
                const float p11v = sr10[m] + cur.y;       // s10[i][q] + s11[q][j]
                if (base > bmax) { bmax = base; ib = m; }  // strict > keeps earliest m
                if (p01v > v01) { v01 = p01v; i01 = m; }
                if (p11v > v11) { v11 = p11v; i11 = m; }
                cur = nxt;
            }
        }
    }
    // Incremental prefetch of next step's operands (overlaps write + barrier).
    if (k < 16) {
        const bool nact = i < kN - (k + 1);
        qjb += j + 1; ++j; pL += kN; ++pR;
        vL = nact ? *pL : 0.f;
        vR = nact ? *pR : 0.f;
    }
    if (act) {
        const float4 w = writeCell(Q4, wsBT, qjbc, i, rbi + k - 1, k,
                                   bmax, ib, vLc, vRc, v01, i01, v11, i11);
        sr11[k] = w.y; sr01[k] = w.z; sr10[k] = w.w;  // constant index (k unrolled)
    }
    (void)jc;
}

// ---- Chunked phases: register row-cache + fw forwarding (verified R4) ----
template <int LP, int C>
__device__ __forceinline__ void preloadRow(int k0, int tid,
                                           const float4* __restrict__ Q4,
                                           float (&r11)[kCMax], float (&r01)[kCMax],
                                           float (&r10)[kCMax]) {
    constexpr int P = 1 << LP;
    const int i = tid >> LP;
    const int l = tid & (P - 1);
    const int mlo = l * C;
    const int mstart = mlo ? mlo : 1;
    const bool act = i < (kN - k0);
#pragma unroll
    for (int c = 0; c < C; ++c) {
        const int m = mstart + c;
        if (act && (m < mlo + C) && (m <= k0 - 1)) {
            const float4 d = Q4[colBaseD(i + m) + i];  // quad(i, i+m), immutable
            r11[c] = d.y; r01[c] = d.z; r10[c] = d.w;
        }
    }
    // Slots with m > k0-1 stay stale: first read at step k=m+1 substitutes fw.
}

template <int LP, int C>
__device__ __forceinline__ void fwInit(int k0, int tid,
                                       const float (&r11)[kCMax], const float (&r01)[kCMax],
                                       const float (&r10)[kCMax],
                                       float& fw11, float& fw01, float& fw10) {
    constexpr int P = 1 << LP;
    const int l = tid & (P - 1);
    const int mlo = l * C;
    const int mstart = mlo ? mlo : 1;
#pragma unroll
    for (int c = 0; c < C; ++c) {
        if (mstart + c == k0 - 1) { fw11 = r11[c]; fw01 = r01[c]; fw10 = r10[c]; }
    }
}

template <int LP, int C>
__device__ __forceinline__ void doStepC(int k, int i, int l, int tid,
                                        float4* __restrict__ Q4,
                                        uint32_t* __restrict__ wsBT,
                                        int& j, int& qjb, int rbi,
                                        const float*& pL, const float*& pR,
                                        float& vL, float& vR,
                                        float (&r11)[kCMax], float (&r01)[kCMax],
                                        float (&r10)[kCMax],
                                        float& fw11, float& fw01, float& fw10) {
    constexpr int P = 1 << LP;
    static_assert(P <= 16, "reductions must stay pure-DPP");
    const bool act = i < kN - k;
    const float vLc = vL, vRc = vR;  // prefetch below overwrites vL/vR
    const int mlo = l * C;
    const int mstart = mlo ? mlo : 1;
    const int mhi = (mlo + C < k) ? (mlo + C) : k;
    const bool waveActive = (((tid & ~63) >> LP) < (kN - k));  // wave-uniform
    const int qjbc = qjb;

    float bmax = -3.0e38f, v01 = -3.0e38f, v11 = -3.0e38f;
    int ib = 0x7FFFFFFF, i01 = 0x7FFFFFFF, i11 = 0x7FFFFFFF;

    const int mf = k - 1;
    const bool lact = waveActive && act && (mstart < mhi);
    float4 cur = make_float4(0.f, 0.f, 0.f, 0.f);
    if (lact) cur = Q4[qjbc + i + mstart];  // column seed quad(i+mstart, j)
    if (act && mlo == 0) {
        bmax = cur.z; ib = 0;  // base(0) = 0 + s01[i+1][j]
        const float p00 = (cur.z + vLc) + kArcBonus;
        v01 = (p00 > kThresh) ? p00 : kNeg; i01 = 0;  // part00 seed
    }
#pragma unroll
    for (int c = 0; c < C; ++c) {
        const int m = mstart + c;
        // Row operands: registers; fresh slot m==k-1 comes from fw (the cell
        // this group computed last step), committed into the cache here.
        const bool isF = (m == mf);
        const float a11 = isF ? fw11 : r11[c];
        const float a01 = isF ? fw01 : r01[c];
        const float a10 = isF ? fw10 : r10[c];
        r11[c] = a11; r01[c] = a01; r10[c] = a10;
        const bool on = lact && (m < mhi);
        if (on) {
            const float4 nxt = Q4[qjbc + i + m + 1];  // quad(q+1, j); imm offset
            const float base = a11 + nxt.z;           // s11[i][q] + s01[q+1][j]
            const float p01v = a01 + cur.x;           // s01[i][q] + s00[q][j]
            const float p11v = a10 + cur.y;           // s10[i][q] + s11[q][j]
            if (base > bmax) { bmax = base; ib = m; }  // strict > keeps earliest m
            if (p01v > v01) { v01 = p01v; i01 = m; }
            if (p11v > v11) { v11 = p11v; i11 = m; }
            cur = nxt;
        }
    }

    // Incremental prefetch of next step's operands (overlaps reduction+barrier).
    {
        const bool nact = i < kN - (k + 1);
        qjb += j + 1; ++j; pL += kN; ++pR;
        vL = nact ? *pL : 0.f;
        vR = nact ? *pR : 0.f;
    }

    if (waveActive) {
        // Value butterfly (pure DPP, VALU pipe only).
        float gB = dppMax<0x141>(dppMax<0x4E>(dppMax<0xB1>(bmax)));
        float g01 = dppMax<0x141>(dppMax<0x4E>(dppMax<0xB1>(v01)));
        float g11 = dppMax<0x141>(dppMax<0x4E>(dppMax<0xB1>(v11)));
        if constexpr (P == 16) {
            gB = dppMax<0x140>(gB); g01 = dppMax<0x140>(g01); g11 = dppMax<0x140>(g11);
        }
        // Earliest-m argmax: mask losers to INT_MAX, min-butterfly (pure DPP).
        int cB = (bmax == gB) ? ib : 0x7FFFFFFF;
        int c01 = (v01 == g01) ? i01 : 0x7FFFFFFF;
        int c11 = (v11 == g11) ? i11 : 0x7FFFFFFF;
        cB = dppMinI<0x141>(dppMinI<0x4E>(dppMinI<0xB1>(cB)));
        c01 = dppMinI<0x141>(dppMinI<0x4E>(dppMinI<0xB1>(c01)));
        c11 = dppMinI<0x141>(dppMinI<0x4E>(dppMinI<0xB1>(c11)));
        if constexpr (P == 16) {
            cB = dppMinI<0x140>(cB); c01 = dppMinI<0x140>(c01); c11 = dppMinI<0x140>(c11);
        }

        // All lanes hold the written-cell values -> fw for next step (m = k).
        // Identical arithmetic to writeCell => bitwise-equal values.
        const float v10f = (gB + vRc) + kArcBonus;
        const float new10 = (v10f > kThresh) ? v10f : kNeg;
        float v11m = g11;
        if (new10 > v11m) v11m = new10;
        fw11 = (v11m > kThresh) ? v11m : kNeg;  // w.y = s11(i,j)
        fw01 = (g01 > kThresh) ? g01 : kNeg;    // w.z = s01(i,j)
        fw10 = (v10f > kThresh) ? v10f : kNeg;  // w.w = s10(i,j)

        if (act && l == 0) {
            writeCell(Q4, wsBT, qjbc, i, rbi + k - 1, k,
                      gB, cB, vLc, vRc, g01, c01, g11, c11);
        }
    }
}

// Phase driver: barrier per step (R4 structure), incremental addressing.
template <int LP, int C>
__device__ __forceinline__ void runPhaseC(int k0, int k1, int tid,
        float4* __restrict__ Q4, uint32_t* __restrict__ wsBT,
        const float* __restrict__ v,
        float (&r11)[kCMax], float (&r01)[kCMax], float (&r10)[kCMax]) {
    constexpr int P = 1 << LP;
    const int i = tid >> LP;
    const int l = tid & (P - 1);
    int j = i + k0;
    int qjb = colBaseD(j);
    const int rbi = rowBase(i & (kN - 1));  // clamp to avoid overflow arith; unused if inactive
    const float* pL = v + (size_t)j * kN + i;
    const float* pR = v + (size_t)i * kN + j;
    const bool a0 = i < kN - k0;
    float vL = a0 ? *pL : 0.f;  // issue loads first: latency hides under preload
    float vR = a0 ? *pR : 0.f;
    preloadRow<LP, C>(k0, tid, Q4, r11, r01, r10);
    float fw11 = kNeg, fw01 = kNeg, fw10 = kNeg;
    fwInit<LP, C>(k0, tid, r11, r01, r10, fw11, fw01, fw10);
    for (int k = k0; k < k1; ++k) {
        doStepC<LP, C>(k, i, l, tid, Q4, wsBT, j, qjb, rbi, pL, pR, vL, vR,
                       r11, r01, r10, fw11, fw01, fw10);
        ldsBarrier();
    }
}

__global__ __launch_bounds__(kThreads) void eisner_dp(
    const float* __restrict__ vinfo,  // [B][N][N] fp32
    float* __restrict__ outS,         // [B][N][N][2][2] fp32 scores
    float* __restrict__ outBT,        // [B][N][N][2][2] fp32 backtrace (integer-valued)
    uint32_t* __restrict__ btPacked)  // [B][kTri] packed backtrace bytes (d_ws)
{
    extern __shared__ float4 Q4[];

    const int tid = threadIdx.x;
    const int b = blockIdx.x;
    const float* v = vinfo + (size_t)b * kN * kN;
    uint32_t* wsBT = btPacked + (size_t)b * kTri;

    // Diagonal quads = 0. Off-diagonal cells need no init (written before read).
    const float4 zeroq = make_float4(0.f, 0.f, 0.f, 0.f);
    if (tid < kN) Q4[colBaseD(tid) + tid] = zeroq;
    __syncthreads();

    // ---- serial phase (k = 1..16), fully unrolled, incremental addressing ----
    {
        const int i = tid;
        float sr11[17], sr01[17], sr10[17];
        int j = i + 1;
        int qjb = colBaseD(j);
        const int rbi = rowBase(i & (kN - 1));
        const float* pL = v + (size_t)j * kN + i;
        const float* pR = v + (size_t)i * kN + j;
        const bool a0 = i < kN - 1;
        float vL = a0 ? *pL : 0.f;
        float vR = a0 ? *pR : 0.f;
#pragma unroll
        for (int k = 1; k <= 16; ++k) {
            doStepSerialReg(k, i, Q4, wsBT, j, qjb, rbi, pL, pR, vL, vR,
                            sr11, sr01, sr10);
            ldsBarrier();
        }
    }

    // Row caches (registers); slots filled by preloadRow + fw commits.
    float r11[kCMax], r01[kCMax], r10[kCMax];
#pragma unroll
    for (int c = 0; c < kCMax; ++c) { r11[c] = kNeg; r01[c] = kNeg; r10[c] = kNeg; }

    // Tight phase table: C sized to each phase's max k (P*C >= k1-1).
    runPhaseC<3, 3>(17, 24, tid, Q4, wsBT, v, r11, r01, r10);   // 8*3=24 >= 23
    runPhaseC<3, 5>(24, 40, tid, Q4, wsBT, v, r11, r01, r10);   // 8*5=40 >= 39
    runPhaseC<3, 7>(40, 56, tid, Q4, wsBT, v, r11, r01, r10);   // 8*7=56 >= 55
    runPhaseC<3, 9>(56, 64, tid, Q4, wsBT, v, r11, r01, r10);   // 8*9=72 >= 63
    runPhaseC<4, 5>(64, 80, tid, Q4, wsBT, v, r11, r01, r10);   // 16*5=80 >= 79
    runPhaseC<4, 7>(80, 112, tid, Q4, wsBT, v, r11, r01, r10);  // 16*7=112 >= 111
    runPhaseC<4, 9>(112, 128, tid, Q4, wsBT, v, r11, r01, r10); // 16*9=144 >= 127

    // Full barrier (drains vmcnt) before reading wsBT back.
    __syncthreads();

    // ---- epilogue: emit full [N][N][2][2] scores + backtrace, coalesced ----
    float4* gS4 = (float4*)(outS + (size_t)b * kN * kN * 4);
    float4* gB4 = (float4*)(outBT + (size_t)b * kN * kN * 4);
    const float4 negq = make_float4(kNeg, kNeg, kNeg, kNeg);
    for (int c = tid; c < kN * kN; c += kThreads) {
        const int i = c >> 7, j = c & (kN - 1);
        if (i < j) {
            const float4 q = Q4[colBaseD(j) + i];
            gS4[c] = make_float4(q.x, q.z, q.w, q.y);  // {s00, s01, s10, s11}
            const uint32_t p = wsBT[rowBase(i) + (j - i - 1)];
            gB4[c] = make_float4((float)(p & 255u), (float)((p >> 8) & 255u),
                                 (float)((p >> 16) & 255u), (float)(p >> 24));
        } else if (i == j) {
            gS4[c] = zeroq;
            gB4[c] = zeroq;
        } else {
            gS4[c] = negq;
            gB4[c] = zeroq;
        }
    }
}

extern "C" void kernel_launch(void* const* d_in, const int* in_sizes, int n_in,
                              void* d_out, int out_size, void* d_ws, size_t ws_size,
                              hipStream_t stream) {
    (void)n_in; (void)out_size; (void)ws_size;
    const float* vinfo = (const float*)d_in[0];  // fp32 [B][N][N]
    const int B = in_sizes[1];                   // b_buffer_size has B elements
    float* outS = (float*)d_out;
    float* outBT = outS + (size_t)B * kN * kN * 4;
    uint32_t* btPacked = (uint32_t*)d_ws;        // needs B*kTri*4 = ~2.1 MB

    hipFuncSetAttribute(reinterpret_cast<const void*>(eisner_dp),
                        hipFuncAttributeMaxDynamicSharedMemorySize, kDynLds);

    eisner_dp<<<dim3(B), dim3(kThreads), kDynLds, stream>>>(vinfo, outS, outBT, btPacked);
}